// Round 1
// baseline (90.289 us; speedup 1.0000x reference)
//
#include <hip/hip_runtime.h>
#include <hip/hip_bf16.h>
#include <math.h>

#define Bc 2
#define Cc 16
#define D4c 48
#define Kc 24
#define Hc 512
#define Wc 960
#define H4c 128
#define W4c 240
#define HW4 (H4c * W4c)   // 30720
#define S4 (Bc * HW4)     // 61440
#define HW1 (Hc * Wc)     // 491520
#define S1 (Bc * HW1)     // 983040

// ---------------------------------------------------------------------------
// Kernel A: channel-reduce feat_l/feat_r with w_red -> Lred[p], Rred[p]
// cost_k(p) = att_topk_k * (Lred[p] + Rred[p - d_k])   (Rred term 0 if w-d<0)
// ---------------------------------------------------------------------------
__global__ void k_featred(const float* __restrict__ fl, const float* __restrict__ fr,
                          const float* __restrict__ wred,
                          float* __restrict__ Lred, float* __restrict__ Rred) {
    int p = blockIdx.x * blockDim.x + threadIdx.x;
    if (p >= S4) return;
    int b  = p / HW4;
    int hw = p - b * HW4;
    const float* flb = fl + (size_t)b * Cc * HW4 + hw;
    const float* frb = fr + (size_t)b * Cc * HW4 + hw;
    float ls = 0.f, rs = 0.f;
#pragma unroll
    for (int c = 0; c < Cc; ++c) {
        ls = fmaf(wred[c],      flb[(size_t)c * HW4], ls);
        rs = fmaf(wred[Cc + c], frb[(size_t)c * HW4], rs);
    }
    Lred[p] = ls;
    Rred[p] = rs;
}

// ---------------------------------------------------------------------------
// Kernel B: one wave (64 lanes) per coarse pixel; lane = disparity (0..47).
// Does: softmax over D, top-24 selection (rank via 48 shuffle broadcasts),
// attention-only regression, sparse cost, top-2 regression.
// ---------------------------------------------------------------------------
__global__ void k_topk(const float* __restrict__ att,
                       const float* __restrict__ Lred, const float* __restrict__ Rred,
                       float* __restrict__ oA4, float* __restrict__ oD4) {
    const int lane = threadIdx.x & 63;
    const int pix  = (blockIdx.x * blockDim.x + threadIdx.x) >> 6;
    if (pix >= S4) return;
    const int b  = pix / HW4;
    const int hw = pix - b * HW4;
    const int w  = hw % W4c;

    const float NEG = -3.0e38f;
    float a = NEG;
    if (lane < D4c) a = att[(size_t)(b * D4c + lane) * HW4 + hw];

    // softmax denominator over all 48 disparities
    float m = a;
#pragma unroll
    for (int off = 32; off; off >>= 1) m = fmaxf(m, __shfl_xor(m, off));
    float e = (lane < D4c) ? expf(a - m) : 0.f;
    float s = e;
#pragma unroll
    for (int off = 32; off; off >>= 1) s += __shfl_xor(s, off);

    // rank under (value desc, index asc) — matches top_k + ascending-sort set
    int cnt = 0;
    for (int j = 0; j < D4c; ++j) {
        float aj = __shfl(a, j);
        cnt += (aj > a || (aj == a && j < lane)) ? 1 : 0;
    }
    const bool sel = (lane < D4c) && (cnt < Kc);

    // attention-only branch: softmax over the K selected RAW values, weight by d
    float ar = sel ? a : NEG;
    float m2 = ar;
#pragma unroll
    for (int off = 32; off; off >>= 1) m2 = fmaxf(m2, __shfl_xor(m2, off));
    float e2 = sel ? expf(a - m2) : 0.f;
    float s2 = e2;
    float n2 = e2 * (float)lane;
#pragma unroll
    for (int off = 32; off; off >>= 1) { s2 += __shfl_xor(s2, off); n2 += __shfl_xor(n2, off); }
    const float predA = n2 / s2;

    // sparse cost at selected disparities
    float cost = NEG;
    if (sel) {
        int src = w - lane;
        float Rs = (src >= 0) ? Rred[pix - lane] : 0.f;
        cost = (e / s) * (Lred[pix] + Rs);
    }

    // top-2 of cost (desc value, tie -> lower disparity), butterfly argmax
    float v1 = cost; int i1 = lane;
#pragma unroll
    for (int off = 32; off; off >>= 1) {
        float ov = __shfl_xor(v1, off);
        int   oi = __shfl_xor(i1, off);
        if (ov > v1 || (ov == v1 && oi < i1)) { v1 = ov; i1 = oi; }
    }
    float c2 = (lane == i1) ? NEG : cost;
    float v2 = c2; int i2 = lane;
#pragma unroll
    for (int off = 32; off; off >>= 1) {
        float ov = __shfl_xor(v2, off);
        int   oi = __shfl_xor(i2, off);
        if (ov > v2 || (ov == v2 && oi < i2)) { v2 = ov; i2 = oi; }
    }
    // softmax over [v1, v2] (v1 >= v2), weighted disparity
    const float r = expf(v2 - v1);
    const float predD = ((float)i1 + r * (float)i2) / (1.f + r);

    if (lane == 0) {
        oA4[pix] = predA;
        oD4[pix] = predD;
    }
}

// ---------------------------------------------------------------------------
// Kernel C: full-res superpixel-guided 4x upsample (both predictions fused).
// ---------------------------------------------------------------------------
__global__ void k_upsample(const float* __restrict__ spx,
                           const float* __restrict__ A4, const float* __restrict__ D4p,
                           float* __restrict__ oA1, float* __restrict__ oD1) {
    int t = blockIdx.x * blockDim.x + threadIdx.x;
    if (t >= S1) return;
    int b  = t / HW1;
    int yx = t - b * HW1;
    int y  = yx / Wc;
    int x  = yx - y * Wc;

    const float* sp = spx + (size_t)b * 9 * HW1 + yx;
    float v[9];
    float m = -3.0e38f;
#pragma unroll
    for (int j = 0; j < 9; ++j) { v[j] = sp[(size_t)j * HW1]; m = fmaxf(m, v[j]); }
    float s = 0.f;
#pragma unroll
    for (int j = 0; j < 9; ++j) { v[j] = expf(v[j] - m); s += v[j]; }

    const int y4 = y >> 2, x4 = x >> 2;
    const float* A4b = A4 + b * HW4;
    const float* D4b = D4p + b * HW4;
    float accA = 0.f, accD = 0.f;
#pragma unroll
    for (int dy = 0; dy < 3; ++dy) {
        int yy = y4 + dy - 1;
#pragma unroll
        for (int dx = 0; dx < 3; ++dx) {
            int xx = x4 + dx - 1;
            int j = dy * 3 + dx;
            if (yy >= 0 && yy < H4c && xx >= 0 && xx < W4c) {
                int p = yy * W4c + xx;
                accA = fmaf(v[j], A4b[p], accA);
                accD = fmaf(v[j], D4b[p], accD);
            }
        }
    }
    const float inv = 4.f / s;
    oA1[t] = accA * inv;
    oD1[t] = accD * inv;
}

extern "C" void kernel_launch(void* const* d_in, const int* in_sizes, int n_in,
                              void* d_out, int out_size, void* d_ws, size_t ws_size,
                              hipStream_t stream) {
    const float* att  = (const float*)d_in[0];  // [B,1,48,128,240]
    const float* fl   = (const float*)d_in[1];  // [B,16,128,240]
    const float* fr   = (const float*)d_in[2];  // [B,16,128,240]
    const float* wred = (const float*)d_in[3];  // [32]
    const float* spx  = (const float*)d_in[4];  // [B,9,512,960]

    float* out = (float*)d_out;
    float* oA4 = out;                 // pred_att_x4 [B,128,240]
    float* oA1 = out + S4;            // pred_att_x1 [B,512,960]
    float* oD4 = out + S4 + S1;       // pred_x4     [B,128,240]
    float* oD1 = out + 2 * S4 + S1;   // pred_x1     [B,512,960]

    // scratch for reduced feature maps (2 * 61440 floats = 480 KiB)
    float *Lred, *Rred;
    if (ws_size >= (size_t)2 * S4 * sizeof(float)) {
        Lred = (float*)d_ws;
        Rred = Lred + S4;
    } else {
        // reuse the pred_att_x1 region as temp scratch; kernel C fully
        // overwrites it afterwards (S1 = 983040 >= 2*S4 = 122880).
        Lred = oA1;
        Rred = oA1 + S4;
    }

    k_featred<<<(S4 + 255) / 256, 256, 0, stream>>>(fl, fr, wred, Lred, Rred);
    k_topk<<<(S4 * 64) / 256, 256, 0, stream>>>(att, Lred, Rred, oA4, oD4);
    k_upsample<<<(S1 + 255) / 256, 256, 0, stream>>>(spx, oA4, oD4, oA1, oD1);
}

// Round 2
// 48.260 us; speedup vs baseline: 1.8709x; 1.8709x over previous
//
#include <hip/hip_runtime.h>
#include <hip/hip_bf16.h>
#include <math.h>

#define Bc 2
#define Cc 16
#define D4c 48
#define Kc 24
#define Hc 512
#define Wc 960
#define H4c 128
#define W4c 240
#define HW4 (H4c * W4c)   // 30720
#define S4 (Bc * HW4)     // 61440
#define HW1 (Hc * Wc)     // 491520
#define S1 (Bc * HW1)     // 983040

// ---------------------------------------------------------------------------
// Kernel A: channel-reduce feat_l/feat_r with w_red -> Lred[p], Rred[p]
// cost_k(p) = att_prob_k * (Lred[p] + Rred[p - d_k])   (Rred term 0 if w-d<0)
// ---------------------------------------------------------------------------
__global__ void k_featred(const float* __restrict__ fl, const float* __restrict__ fr,
                          const float* __restrict__ wred,
                          float* __restrict__ Lred, float* __restrict__ Rred) {
    int p = blockIdx.x * blockDim.x + threadIdx.x;
    if (p >= S4) return;
    int b  = p / HW4;
    int hw = p - b * HW4;
    const float* flb = fl + (size_t)b * Cc * HW4 + hw;
    const float* frb = fr + (size_t)b * Cc * HW4 + hw;
    float ls = 0.f, rs = 0.f;
#pragma unroll
    for (int c = 0; c < Cc; ++c) {
        ls = fmaf(wred[c],      flb[(size_t)c * HW4], ls);
        rs = fmaf(wred[Cc + c], frb[(size_t)c * HW4], rs);
    }
    Lred[p] = ls;
    Rred[p] = rs;
}

// ---------------------------------------------------------------------------
// Kernel B: one THREAD per coarse pixel; 48 disparities held in registers.
// Ranking = pairwise beat-count (1128 pairs, fully unrolled, no shuffles).
// Loads are lane-coalesced (lane = consecutive pixel, loop over d-planes).
// ---------------------------------------------------------------------------
__global__ __launch_bounds__(256) void k_topk(const float* __restrict__ att,
                       const float* __restrict__ Lred, const float* __restrict__ Rred,
                       float* __restrict__ oA4, float* __restrict__ oD4) {
    const int pix = blockIdx.x * blockDim.x + threadIdx.x;
    if (pix >= S4) return;
    const int b  = pix / HW4;
    const int hw = pix - b * HW4;
    const int w  = hw % W4c;

    // ---- load the 48 raw logits (each iteration coalesced across lanes) ----
    const float* ap = att + (size_t)b * D4c * HW4 + hw;
    float a[D4c];
#pragma unroll
    for (int i = 0; i < D4c; ++i) a[i] = ap[(size_t)i * HW4];
    const float L = Lred[pix];

    // ---- global max ----
    float m = a[0];
#pragma unroll
    for (int i = 1; i < D4c; ++i) m = fmaxf(m, a[i]);

    // ---- pairwise beat-count: bc[i] = #{j : j beats i} under (val desc, idx asc)
    // For pair i<j: i beats j iff a[i] >= a[j]. Init bc[i] = 47-i, then
    // bc[i] -= b, bc[j] += b.  Selected iff bc[i] < 24.
    int bc[D4c];
#pragma unroll
    for (int i = 0; i < D4c; ++i) bc[i] = (D4c - 1) - i;
#pragma unroll
    for (int i = 0; i < D4c; ++i) {
#pragma unroll
        for (int j = i + 1; j < D4c; ++j) {
            int bb = (a[i] >= a[j]) ? 1 : 0;
            bc[i] -= bb;
            bc[j] += bb;
        }
    }

    // ---- e_i = exp(a_i - m); s = full softmax denominator ----
    float s = 0.f;
#pragma unroll
    for (int i = 0; i < D4c; ++i) { a[i] = expf(a[i] - m); s += a[i]; }

    // ---- attention-only regression: softmax over the selected RAW values.
    // max of selected == global max, so e2_i == e_i.
    float s2 = 0.f, n2 = 0.f;
#pragma unroll
    for (int i = 0; i < D4c; ++i) {
        float ei = (bc[i] < Kc) ? a[i] : 0.f;
        s2 += ei;
        n2 = fmaf(ei, (float)i, n2);
    }
    const float predA = n2 / s2;

    // ---- sparse cost + top-2 (scale 1/s folded into the final exp) ----
    const float NEG = -3.0e38f;
    float v1 = NEG, v2 = NEG;
    int   i1 = 0,   i2 = 0;
#pragma unroll
    for (int i = 0; i < D4c; ++i) {
        float R = (w - i >= 0) ? Rred[pix - i] : 0.f;
        float c = (bc[i] < Kc) ? a[i] * (L + R) : NEG;
        if (c > v1)      { v2 = v1; i2 = i1; v1 = c; i1 = i; }
        else if (c > v2) { v2 = c; i2 = i; }
    }
    const float r = expf((v2 - v1) / s);   // actual cost delta = (v2-v1)/s
    const float predD = ((float)i1 + r * (float)i2) / (1.f + r);

    oA4[pix] = predA;
    oD4[pix] = predD;
}

// ---------------------------------------------------------------------------
// Kernel C: full-res superpixel-guided 4x upsample (both predictions fused).
// ---------------------------------------------------------------------------
__global__ void k_upsample(const float* __restrict__ spx,
                           const float* __restrict__ A4, const float* __restrict__ D4p,
                           float* __restrict__ oA1, float* __restrict__ oD1) {
    int t = blockIdx.x * blockDim.x + threadIdx.x;
    if (t >= S1) return;
    int b  = t / HW1;
    int yx = t - b * HW1;
    int y  = yx / Wc;
    int x  = yx - y * Wc;

    const float* sp = spx + (size_t)b * 9 * HW1 + yx;
    float v[9];
    float m = -3.0e38f;
#pragma unroll
    for (int j = 0; j < 9; ++j) { v[j] = sp[(size_t)j * HW1]; m = fmaxf(m, v[j]); }
    float s = 0.f;
#pragma unroll
    for (int j = 0; j < 9; ++j) { v[j] = expf(v[j] - m); s += v[j]; }

    const int y4 = y >> 2, x4 = x >> 2;
    const float* A4b = A4 + b * HW4;
    const float* D4b = D4p + b * HW4;
    float accA = 0.f, accD = 0.f;
#pragma unroll
    for (int dy = 0; dy < 3; ++dy) {
        int yy = y4 + dy - 1;
#pragma unroll
        for (int dx = 0; dx < 3; ++dx) {
            int xx = x4 + dx - 1;
            int j = dy * 3 + dx;
            if (yy >= 0 && yy < H4c && xx >= 0 && xx < W4c) {
                int p = yy * W4c + xx;
                accA = fmaf(v[j], A4b[p], accA);
                accD = fmaf(v[j], D4b[p], accD);
            }
        }
    }
    const float inv = 4.f / s;
    oA1[t] = accA * inv;
    oD1[t] = accD * inv;
}

extern "C" void kernel_launch(void* const* d_in, const int* in_sizes, int n_in,
                              void* d_out, int out_size, void* d_ws, size_t ws_size,
                              hipStream_t stream) {
    const float* att  = (const float*)d_in[0];  // [B,1,48,128,240]
    const float* fl   = (const float*)d_in[1];  // [B,16,128,240]
    const float* fr   = (const float*)d_in[2];  // [B,16,128,240]
    const float* wred = (const float*)d_in[3];  // [32]
    const float* spx  = (const float*)d_in[4];  // [B,9,512,960]

    float* out = (float*)d_out;
    float* oA4 = out;                 // pred_att_x4 [B,128,240]
    float* oA1 = out + S4;            // pred_att_x1 [B,512,960]
    float* oD4 = out + S4 + S1;       // pred_x4     [B,128,240]
    float* oD1 = out + 2 * S4 + S1;   // pred_x1     [B,512,960]

    // scratch for reduced feature maps (2 * 61440 floats = 480 KiB)
    float *Lred, *Rred;
    if (ws_size >= (size_t)2 * S4 * sizeof(float)) {
        Lred = (float*)d_ws;
        Rred = Lred + S4;
    } else {
        // reuse the pred_att_x1 region as temp scratch; kernel C fully
        // overwrites it afterwards (S1 >= 2*S4).
        Lred = oA1;
        Rred = oA1 + S4;
    }

    k_featred<<<(S4 + 255) / 256, 256, 0, stream>>>(fl, fr, wred, Lred, Rred);
    k_topk<<<(S4 + 255) / 256, 256, 0, stream>>>(att, Lred, Rred, oA4, oD4);
    k_upsample<<<(S1 + 255) / 256, 256, 0, stream>>>(spx, oA4, oD4, oA1, oD1);
}